// Round 1
// 190.341 us; speedup vs baseline: 1.0988x; 1.0988x over previous
//
#include <hip/hip_runtime.h>
#include <hip/hip_bf16.h>
#include <stdint.h>

// Problem constants
#define IN_DIM  512
#define OUT_DIM 512
#define BATCH   16384
#define KPF     12               // 11 basis funcs + 1 base-activation column
#define BM      128
#define BN      256
#define BK      96               // 8 features * 12 = 3 mfma K-steps of 32
#define KCH     64               // 6144 / 96
#define TSTR    104              // padded row stride (bf16): 208B = 13 x 16B chunks
#define TILE_E  (BN * TSTR)      // 26624 elems per W2 k-tile

typedef __bf16 bf16;
typedef __bf16 bf16x8 __attribute__((ext_vector_type(8)));
typedef float  f32x4  __attribute__((ext_vector_type(4)));

__device__ __forceinline__ void gl2lds16(const void* g, void* l) {
    __builtin_amdgcn_global_load_lds((__attribute__((address_space(1))) uint32_t*)g,
                                     (__attribute__((address_space(3))) uint32_t*)l,
                                     16, 0, 0);
}
__device__ __forceinline__ uint bfbits(float v) {
    union { bf16 h; ushort u; } c; c.h = (bf16)v; return (uint)c.u;
}
__device__ __forceinline__ uint pk2(float lo, float hi) {
    return bfbits(lo) | (bfbits(hi) << 16);
}

// ---------------------------------------------------------------------------
// Pack W into DMA-linear tiled layout (unchanged):
//   W2[g][kc][r][c]  (g = n/256, kc = k-chunk, r = n%256, c in [0,104) padded)
// ---------------------------------------------------------------------------
__global__ void pack_w(const float* __restrict__ coeff,
                       const float* __restrict__ sbase,
                       const float* __restrict__ sspl,
                       bf16* __restrict__ W2) {
    __shared__ float cs[11 * 256];
    const int tid  = threadIdx.x;
    const int base = blockIdx.x * 256;                 // first gid of block
    const float* src = coeff + (size_t)base * 11;
#pragma unroll
    for (int j = 0; j < 11; ++j) cs[j * 256 + tid] = src[j * 256 + tid];
    __syncthreads();
    const int gid = base + tid;                        // o*512 + i
    const int o = gid >> 9, i = gid & 511;
    const float s = sspl[gid];
    const float* cp = cs + tid * 11;
    union { bf16 hh[12]; uint2 uu[3]; } pk;
#pragma unroll
    for (int k = 0; k < 11; ++k) pk.hh[k] = (bf16)(cp[k] * s);
    pk.hh[11] = (bf16)sbase[gid];
    const int g = o >> 8, r = o & 255, kc = i >> 3, ic = i & 7;
    uint2* dst = (uint2*)(W2 + ((size_t)(g * 64 + kc) * 256 + r) * TSTR + ic * 12);
    dst[0] = pk.uu[0]; dst[1] = pk.uu[1]; dst[2] = pk.uu[2];
}

// ---------------------------------------------------------------------------
// Fused KAN kernel, producer/consumer wave specialization.
// 512 threads = 8 waves; waves 0-3 = consumers (pure MFMA, 64x128 tile each),
// waves 4-7 = producers (spline eval + global_load_lds DMA + vmcnt drain).
// One producer + one consumer per SIMD -> eval VALU overlaps MFMA.
// ---------------------------------------------------------------------------
__global__ void __launch_bounds__(512, 2) kan_gemm(
    const float* __restrict__ xg,
    const float* __restrict__ gridp,
    const float* __restrict__ bias,
    const bf16*  __restrict__ W2,
    float* __restrict__ out)
{
    __shared__ bf16 Abuf[2 * BM * TSTR];   //  53248 B
    __shared__ bf16 Bbuf[2 * BN * TSTR];   // 106496 B   (total 159744 of 160 KiB)

    const int tid  = threadIdx.x;
    const int lane = tid & 63;
    const int wave = tid >> 6;
    const bool producer = (wave >= 4);
    const int g  = blockIdx.x;             // n-half, grid.x = 2
    const int n0 = g * BN;
    const int m0 = blockIdx.y * BM;

    const float g0    = gridp[0];
    const float inv_h = 1.0f / (gridp[1] - gridp[0]);

    const bf16* Wg = W2 + (size_t)g * KCH * TILE_E;

    // ---- producer assignment: 256 threads cover 128 rows x 2 feature-quads
    const int pw    = wave & 3;            // producer wave id 0..3
    const int pt    = tid & 255;
    const int row_e = pt & 127;
    const int fq    = pt >> 7;             // 0..1 -> features 4*fq .. 4*fq+3
    const float4* xp = (const float4*)(xg + (size_t)(m0 + row_e) * IN_DIM);
    // x(kc) for this thread = xp[2*kc + fq]  (floats kc*8 + 4*fq .. +3)

    // ---- consumer assignment: 4 waves, 64x128 wave tiles (2m x 2n)
    const int wm = wave & 1, wn = (wave >> 1) & 1;
    const int lr = lane & 15, lq = lane >> 4;

    f32x4 acc[4][8];
    float4 xn;                             // producer x prefetch register

    // one local B-spline eval -> 6 packed dwords
    auto evalOne = [&](float xv, uint* De) {
        float f  = __builtin_fmaf(xv, inv_h, -g0 * inv_h);
        f = fminf(fmaxf(f, 7.0f), 14.9999f);
        float fj = floorf(f);
        int   j0 = (int)fj;
        float t  = f - fj;
        float t1 = t + 1.0f, t2 = t + 2.0f, t3 = t + 3.0f;
        float s1 = 1.0f - t, s2 = 2.0f - t, s3 = 3.0f - t, s4 = 4.0f - t;
        float a0 = 0.5f * t, a1 = 0.5f * s1;
        const float i3 = (1.0f / 3.0f);
        float b0 = t  * a0 * i3;
        float b1 = (t1 * a1 + s2 * a0) * i3;
        float b2 = s1 * a1 * i3;
        float c0 = t  * b0 * 0.25f;
        float c1 = (t1 * b1 + s3 * b0) * 0.25f;
        float c2 = (t2 * b2 + s2 * b1) * 0.25f;
        float c3 = s1 * b2 * 0.25f;
        float w0 = t  * c0 * 0.2f;
        float w1 = (t1 * c1 + s4 * c0) * 0.2f;
        float w2 = (t2 * c2 + s3 * c1) * 0.2f;
        float w3 = (t3 * c3 + s2 * c2) * 0.2f;
        float w4 = s1 * c3 * 0.2f;
        const int q0 = j0 - 4;             // [3,10]
        const int rr = q0 & 1;
        const int d  = q0 >> 1;            // [1,5]
        uint P0 = pk2(w4, w3), P1 = pk2(w2, w1), P2 = bfbits(w0);
        uint A0 = rr ? (P0 << 16)                : P0;
        uint A1 = rr ? ((P0 >> 16) | (P1 << 16)) : P1;
        uint A2 = rr ? ((P1 >> 16) | (P2 << 16)) : P2;
        De[0] = 0u;
        De[1] = (d == 1) ? A0 : 0u;
        De[2] = (d == 2) ? A0 : ((d == 1) ? A1 : 0u);
        De[3] = (d == 3) ? A0 : ((d == 2) ? A1 : ((d == 1) ? A2 : 0u));
        De[4] = (d == 4) ? A0 : ((d == 3) ? A1 : ((d == 2) ? A2 : 0u));
        uint D5 = (d == 5) ? A0 : ((d == 4) ? A1 : ((d == 3) ? A2 : 0u));
        De[5] = (D5 & 0xFFFFu) | (bfbits(xv + __sinf(xv)) << 16);
    };
    // eval 4 consecutive features (one float4 of x) -> 96B contiguous A write
    auto evalQuad = [&](float4 xv, bf16* Adst) {
        uint D[24];
        evalOne(xv.x, D);
        evalOne(xv.y, D + 6);
        evalOne(xv.z, D + 12);
        evalOne(xv.w, D + 18);
        uint4* awr = (uint4*)(Adst + row_e * TSTR + fq * 48);  // 96B, 16B-aligned
        awr[0] = make_uint4(D[0],  D[1],  D[2],  D[3]);
        awr[1] = make_uint4(D[4],  D[5],  D[6],  D[7]);
        awr[2] = make_uint4(D[8],  D[9],  D[10], D[11]);
        awr[3] = make_uint4(D[12], D[13], D[14], D[15]);
        awr[4] = make_uint4(D[16], D[17], D[18], D[19]);
        awr[5] = make_uint4(D[20], D[21], D[22], D[23]);
    };
    auto dmaB = [&](int kc, bf16* Bdst) {
        const bf16* wsc = Wg + (size_t)kc * TILE_E;
#pragma unroll
        for (int j = 0; j < 13; ++j) {     // 4 producer waves x 13 = 52 issues
            const int iss = pw + 4 * j;
            gl2lds16(wsc + iss * 512 + lane * 8, Bdst + iss * 512);
        }
    };

    // Prologue
    if (producer) {
        float4 xc = xp[fq];                // x(0)
        xn = xp[2 + fq];                   // x(1)
        dmaB(0, Bbuf);
        evalQuad(xc, Abuf);
    } else {
#pragma unroll
        for (int mt = 0; mt < 4; ++mt)
#pragma unroll
            for (int nt = 0; nt < 8; ++nt) { f32x4 z = {0.f,0.f,0.f,0.f}; acc[mt][nt] = z; }
    }
    __syncthreads();                       // A0 visible, B0 DMA drained (by producers)

    for (int kc = 0; kc < KCH; ++kc) {
        const int p = kc & 1;
        if (producer) {
            if (kc < KCH - 1) {
                dmaB(kc + 1, Bbuf + (p ^ 1) * BN * TSTR);
                float4 xt = xp[(((kc + 2) & (KCH - 1)) << 1) + fq];  // prefetch x(kc+2)
                evalQuad(xn, Abuf + (p ^ 1) * BM * TSTR);            // eval chunk kc+1
                xn = xt;
            }
        } else {
            const bf16* Ap = Abuf + p * BM * TSTR;
            const bf16* Bp = Bbuf + p * BN * TSTR;
#pragma unroll
            for (int s = 0; s < 3; ++s) {
                bf16x8 af[4], bfv[8];
#pragma unroll
                for (int mt = 0; mt < 4; ++mt)
                    af[mt] = *(const bf16x8*)&Ap[(wm * 64 + mt * 16 + lr) * TSTR + s * 32 + lq * 8];
#pragma unroll
                for (int nt = 0; nt < 8; ++nt)
                    bfv[nt] = *(const bf16x8*)&Bp[(wn * 128 + nt * 16 + lr) * TSTR + s * 32 + lq * 8];
#pragma unroll
                for (int mt = 0; mt < 4; ++mt)
#pragma unroll
                    for (int nt = 0; nt < 8; ++nt)
                        acc[mt][nt] = __builtin_amdgcn_mfma_f32_16x16x32_bf16(
                            af[mt], bfv[nt], acc[mt][nt], 0, 0, 0);
            }
        }
        __syncthreads();   // buffer p free; p^1 eval-writes + DMA visible
    }

    // Epilogue (consumers only): C/D layout col = lane&15, row = (lane>>4)*4 + reg
    if (!producer) {
#pragma unroll
        for (int nt = 0; nt < 8; ++nt) {
            const int gcol = n0 + wn * 128 + nt * 16 + lr;
            const float bv = bias[gcol];
#pragma unroll
            for (int mt = 0; mt < 4; ++mt) {
#pragma unroll
                for (int i = 0; i < 4; ++i) {
                    const int grow = m0 + wm * 64 + mt * 16 + lq * 4 + i;
                    out[(size_t)grow * OUT_DIM + gcol] = acc[mt][nt][i] + bv;
                }
            }
        }
    }
}

// ---------------------------------------------------------------------------
extern "C" void kernel_launch(void* const* d_in, const int* in_sizes, int n_in,
                              void* d_out, int out_size, void* d_ws, size_t ws_size,
                              hipStream_t stream) {
    const float* x     = (const float*)d_in[0];
    const float* gridv = (const float*)d_in[1];
    const float* coeff = (const float*)d_in[2];
    const float* sbase = (const float*)d_in[3];
    const float* sspl  = (const float*)d_in[4];
    const float* bias  = (const float*)d_in[5];
    float* out = (float*)d_out;
    bf16*  W2  = (bf16*)d_ws;   // 2*64*26624*2 = 6.8 MB workspace

    pack_w<<<dim3((OUT_DIM * IN_DIM) / 256), 256, 0, stream>>>(coeff, sbase, sspl, W2);
    kan_gemm<<<dim3(OUT_DIM / BN, BATCH / BM), 512, 0, stream>>>(x, gridv, bias, W2, out);
}

// Round 2
// 188.333 us; speedup vs baseline: 1.1105x; 1.0107x over previous
//
#include <hip/hip_runtime.h>
#include <hip/hip_bf16.h>
#include <stdint.h>

// Problem constants
#define IN_DIM  512
#define OUT_DIM 512
#define BATCH   16384
#define KPF     12               // 11 basis funcs + 1 base-activation column
#define BM      128
#define BN      256
#define BK      96               // 8 features * 12 = 3 mfma K-steps of 32
#define KCH     64               // 6144 / 96
#define TSTR    104              // padded row stride (bf16): 208B = 13 x 16B chunks
#define TILE_E  (BN * TSTR)      // 26624 elems per W2 k-tile

typedef __bf16 bf16;
typedef __bf16 bf16x8 __attribute__((ext_vector_type(8)));
typedef float  f32x4  __attribute__((ext_vector_type(4)));

__device__ __forceinline__ void gl2lds16(const void* g, void* l) {
    __builtin_amdgcn_global_load_lds((__attribute__((address_space(1))) uint32_t*)g,
                                     (__attribute__((address_space(3))) uint32_t*)l,
                                     16, 0, 0);
}
__device__ __forceinline__ uint bfbits(float v) {
    union { bf16 h; ushort u; } c; c.h = (bf16)v; return (uint)c.u;
}
__device__ __forceinline__ uint pk2(float lo, float hi) {
    return bfbits(lo) | (bfbits(hi) << 16);
}

// ---------------------------------------------------------------------------
// Pack W into DMA-linear tiled layout (unchanged):
//   W2[g][kc][r][c]  (g = n/256, kc = k-chunk, r = n%256, c in [0,104) padded)
// ---------------------------------------------------------------------------
__global__ void pack_w(const float* __restrict__ coeff,
                       const float* __restrict__ sbase,
                       const float* __restrict__ sspl,
                       bf16* __restrict__ W2) {
    __shared__ float cs[11 * 256];
    const int tid  = threadIdx.x;
    const int base = blockIdx.x * 256;                 // first gid of block
    const float* src = coeff + (size_t)base * 11;
#pragma unroll
    for (int j = 0; j < 11; ++j) cs[j * 256 + tid] = src[j * 256 + tid];
    __syncthreads();
    const int gid = base + tid;                        // o*512 + i
    const int o = gid >> 9, i = gid & 511;
    const float s = sspl[gid];
    const float* cp = cs + tid * 11;
    union { bf16 hh[12]; uint2 uu[3]; } pk;
#pragma unroll
    for (int k = 0; k < 11; ++k) pk.hh[k] = (bf16)(cp[k] * s);
    pk.hh[11] = (bf16)sbase[gid];
    const int g = o >> 8, r = o & 255, kc = i >> 3, ic = i & 7;
    uint2* dst = (uint2*)(W2 + ((size_t)(g * 64 + kc) * 256 + r) * TSTR + ic * 12);
    dst[0] = pk.uu[0]; dst[1] = pk.uu[1]; dst[2] = pk.uu[2];
}

// ---------------------------------------------------------------------------
// Fused KAN kernel, producer/consumer wave specialization, 12 waves.
// 768 threads: waves 0-7 = consumers (64x64 tiles, 2 MFMA waves per SIMD),
// waves 8-11 = producers (spline eval + global_load_lds DMA + vmcnt drain).
// Per SIMD: 2 consumers + 1 producer -> matrix pipe stays fed when one
// consumer stalls on LDS.
// ---------------------------------------------------------------------------
__global__ void __launch_bounds__(768, 3) kan_gemm(
    const float* __restrict__ xg,
    const float* __restrict__ gridp,
    const float* __restrict__ bias,
    const bf16*  __restrict__ W2,
    float* __restrict__ out)
{
    __shared__ bf16 Abuf[2 * BM * TSTR];   //  53248 B
    __shared__ bf16 Bbuf[2 * BN * TSTR];   // 106496 B   (total 159744 of 160 KiB)

    const int tid  = threadIdx.x;
    const int lane = tid & 63;
    const int wave = tid >> 6;
    const bool producer = (wave >= 8);
    const int g  = blockIdx.x;             // n-half, grid.x = 2
    const int n0 = g * BN;
    const int m0 = blockIdx.y * BM;

    const float g0    = gridp[0];
    const float inv_h = 1.0f / (gridp[1] - gridp[0]);

    const bf16* Wg = W2 + (size_t)g * KCH * TILE_E;

    // ---- producer assignment: 256 threads cover 128 rows x 2 feature-quads
    const int pw    = wave - 8;            // producer wave id 0..3
    const int pt    = tid - 512;           // 0..255 (producers only)
    const int row_e = pt & 127;
    const int fq    = (pt >> 7) & 1;       // 0..1 -> features 4*fq .. 4*fq+3
    const float4* xp = (const float4*)(xg + (size_t)(m0 + (row_e & 127)) * IN_DIM);
    // x(kc) for this thread = xp[2*kc + fq]  (floats kc*8 + 4*fq .. +3)

    // ---- consumer assignment: 8 waves, 64x64 wave tiles (2m x 4n)
    const int wm = wave & 1, wn = wave >> 1;     // wn in 0..3 for consumers
    const int lr = lane & 15, lq = lane >> 4;

    f32x4 acc[4][4];
    float4 xn;                             // producer x prefetch register

    // one local B-spline eval -> 6 packed dwords
    auto evalOne = [&](float xv, uint* De) {
        float f  = __builtin_fmaf(xv, inv_h, -g0 * inv_h);
        f = fminf(fmaxf(f, 7.0f), 14.9999f);
        float fj = floorf(f);
        int   j0 = (int)fj;
        float t  = f - fj;
        float t1 = t + 1.0f, t2 = t + 2.0f, t3 = t + 3.0f;
        float s1 = 1.0f - t, s2 = 2.0f - t, s3 = 3.0f - t, s4 = 4.0f - t;
        float a0 = 0.5f * t, a1 = 0.5f * s1;
        const float i3 = (1.0f / 3.0f);
        float b0 = t  * a0 * i3;
        float b1 = (t1 * a1 + s2 * a0) * i3;
        float b2 = s1 * a1 * i3;
        float c0 = t  * b0 * 0.25f;
        float c1 = (t1 * b1 + s3 * b0) * 0.25f;
        float c2 = (t2 * b2 + s2 * b1) * 0.25f;
        float c3 = s1 * b2 * 0.25f;
        float w0 = t  * c0 * 0.2f;
        float w1 = (t1 * c1 + s4 * c0) * 0.2f;
        float w2 = (t2 * c2 + s3 * c1) * 0.2f;
        float w3 = (t3 * c3 + s2 * c2) * 0.2f;
        float w4 = s1 * c3 * 0.2f;
        const int q0 = j0 - 4;             // [3,10]
        const int rr = q0 & 1;
        const int d  = q0 >> 1;            // [1,5]
        uint P0 = pk2(w4, w3), P1 = pk2(w2, w1), P2 = bfbits(w0);
        uint A0 = rr ? (P0 << 16)                : P0;
        uint A1 = rr ? ((P0 >> 16) | (P1 << 16)) : P1;
        uint A2 = rr ? ((P1 >> 16) | (P2 << 16)) : P2;
        De[0] = 0u;
        De[1] = (d == 1) ? A0 : 0u;
        De[2] = (d == 2) ? A0 : ((d == 1) ? A1 : 0u);
        De[3] = (d == 3) ? A0 : ((d == 2) ? A1 : ((d == 1) ? A2 : 0u));
        De[4] = (d == 4) ? A0 : ((d == 3) ? A1 : ((d == 2) ? A2 : 0u));
        uint D5 = (d == 5) ? A0 : ((d == 4) ? A1 : ((d == 3) ? A2 : 0u));
        De[5] = (D5 & 0xFFFFu) | (bfbits(xv + __sinf(xv)) << 16);
    };
    // eval 4 consecutive features (one float4 of x) -> 96B contiguous A write
    auto evalQuad = [&](float4 xv, bf16* Adst) {
        uint D[24];
        evalOne(xv.x, D);
        evalOne(xv.y, D + 6);
        evalOne(xv.z, D + 12);
        evalOne(xv.w, D + 18);
        uint4* awr = (uint4*)(Adst + row_e * TSTR + fq * 48);  // 96B, 16B-aligned
        awr[0] = make_uint4(D[0],  D[1],  D[2],  D[3]);
        awr[1] = make_uint4(D[4],  D[5],  D[6],  D[7]);
        awr[2] = make_uint4(D[8],  D[9],  D[10], D[11]);
        awr[3] = make_uint4(D[12], D[13], D[14], D[15]);
        awr[4] = make_uint4(D[16], D[17], D[18], D[19]);
        awr[5] = make_uint4(D[20], D[21], D[22], D[23]);
    };
    auto dmaB = [&](int kc, bf16* Bdst) {
        const bf16* wsc = Wg + (size_t)kc * TILE_E;
#pragma unroll
        for (int j = 0; j < 13; ++j) {     // 4 producer waves x 13 = 52 issues
            const int iss = pw + 4 * j;
            gl2lds16(wsc + iss * 512 + lane * 8, Bdst + iss * 512);
        }
    };

    // Prologue
    if (producer) {
        float4 xc = xp[fq];                // x(0)
        xn = xp[2 + fq];                   // x(1)
        dmaB(0, Bbuf);
        evalQuad(xc, Abuf);
    } else {
#pragma unroll
        for (int mt = 0; mt < 4; ++mt)
#pragma unroll
            for (int nt = 0; nt < 4; ++nt) { f32x4 z = {0.f,0.f,0.f,0.f}; acc[mt][nt] = z; }
    }
    __syncthreads();                       // A0 visible, B0 DMA drained (by producers)

    for (int kc = 0; kc < KCH; ++kc) {
        const int p = kc & 1;
        if (producer) {
            if (kc < KCH - 1) {
                dmaB(kc + 1, Bbuf + (p ^ 1) * BN * TSTR);
                float4 xt = xp[(((kc + 2) & (KCH - 1)) << 1) + fq];  // prefetch x(kc+2)
                evalQuad(xn, Abuf + (p ^ 1) * BM * TSTR);            // eval chunk kc+1
                xn = xt;
            }
        } else {
            const bf16* Ap = Abuf + p * BM * TSTR;
            const bf16* Bp = Bbuf + p * BN * TSTR;
#pragma unroll
            for (int s = 0; s < 3; ++s) {
                bf16x8 af[4], bfv[4];
#pragma unroll
                for (int mt = 0; mt < 4; ++mt)
                    af[mt] = *(const bf16x8*)&Ap[(wm * 64 + mt * 16 + lr) * TSTR + s * 32 + lq * 8];
#pragma unroll
                for (int nt = 0; nt < 4; ++nt)
                    bfv[nt] = *(const bf16x8*)&Bp[(wn * 64 + nt * 16 + lr) * TSTR + s * 32 + lq * 8];
                __builtin_amdgcn_s_setprio(1);
#pragma unroll
                for (int mt = 0; mt < 4; ++mt)
#pragma unroll
                    for (int nt = 0; nt < 4; ++nt)
                        acc[mt][nt] = __builtin_amdgcn_mfma_f32_16x16x32_bf16(
                            af[mt], bfv[nt], acc[mt][nt], 0, 0, 0);
                __builtin_amdgcn_s_setprio(0);
            }
        }
        __syncthreads();   // buffer p free; p^1 eval-writes + DMA visible
    }

    // Epilogue (consumers only): C/D layout col = lane&15, row = (lane>>4)*4 + reg
    if (!producer) {
#pragma unroll
        for (int nt = 0; nt < 4; ++nt) {
            const int gcol = n0 + wn * 64 + nt * 16 + lr;
            const float bv = bias[gcol];
#pragma unroll
            for (int mt = 0; mt < 4; ++mt) {
#pragma unroll
                for (int i = 0; i < 4; ++i) {
                    const int grow = m0 + wm * 64 + mt * 16 + lq * 4 + i;
                    out[(size_t)grow * OUT_DIM + gcol] = acc[mt][nt][i] + bv;
                }
            }
        }
    }
}

// ---------------------------------------------------------------------------
extern "C" void kernel_launch(void* const* d_in, const int* in_sizes, int n_in,
                              void* d_out, int out_size, void* d_ws, size_t ws_size,
                              hipStream_t stream) {
    const float* x     = (const float*)d_in[0];
    const float* gridv = (const float*)d_in[1];
    const float* coeff = (const float*)d_in[2];
    const float* sbase = (const float*)d_in[3];
    const float* sspl  = (const float*)d_in[4];
    const float* bias  = (const float*)d_in[5];
    float* out = (float*)d_out;
    bf16*  W2  = (bf16*)d_ws;   // 2*64*26624*2 = 6.8 MB workspace

    pack_w<<<dim3((OUT_DIM * IN_DIM) / 256), 256, 0, stream>>>(coeff, sbase, sspl, W2);
    kan_gemm<<<dim3(OUT_DIM / BN, BATCH / BM), 768, 0, stream>>>(x, gridv, bias, W2, out);
}